// Round 7
// baseline (1735.984 us; speedup 1.0000x reference)
//
#include <hip/hip_runtime.h>
#include <cstdint>
#include <cstddef>

#define B_    16
#define C_    256
#define HW_   64
#define N_    4096      // 64*64 spatial
#define K_    512
#define NROW_ 65536     // B_*N_

typedef __attribute__((ext_vector_type(8))) __bf16 bf16x8;
typedef __attribute__((ext_vector_type(4))) float floatx4;
typedef __attribute__((address_space(3))) __bf16 lds_bf16;
typedef __attribute__((address_space(1))) const __bf16 glob_bf16;

struct P2 { float v1; int k1; float v2; int k2; };

__device__ __forceinline__ bool lexless(float v, int k, float bv, int bk) {
    return (v < bv) || (v == bv && k < bk);
}
__device__ __forceinline__ void ins2(float v, int k, float& v1, int& k1, float& v2, int& k2) {
    if (lexless(v, k, v1, k1)) { v2 = v1; k2 = k1; v1 = v; k1 = k; }
    else if (lexless(v, k, v2, k2)) { v2 = v; k2 = k; }
}

// Bpack layout: [ct 8][plane 2][cq 4][n 512][i 8] bf16, 512 KB.
// Slice s = (ct, plane) is a contiguous 32 KB block.

// ---------------- kernel 1: codebook prep: e2 + packed bf16 hi/lo tiles -------
__global__ void prep_kernel(const float* __restrict__ cb, float* __restrict__ e2,
                            __bf16* __restrict__ Bpack, double* __restrict__ lossAcc) {
    int n = blockIdx.x, t = threadIdx.x;
    if (n == 0 && t == 0) *lossAcc = 0.0;
    float4 v = *(const float4*)(cb + (size_t)n * C_ + t * 4);
    float vv[4] = {v.x, v.y, v.z, v.w};
    __bf16 h[4], l[4];
    float s = 0.f;
    #pragma unroll
    for (int i = 0; i < 4; ++i) {
        h[i] = (__bf16)vv[i];
        l[i] = (__bf16)(vv[i] - (float)h[i]);
        s = fmaf(vv[i], vv[i], s);
    }
    int ct = t >> 3, cq = (t >> 1) & 3, i0 = (t & 1) * 4;
    size_t base = (size_t)ct * 32768;
    size_t off0 = base + ((size_t)(0 * 4 + cq) * 512 + n) * 8 + i0;   // hi plane
    size_t off1 = base + ((size_t)(1 * 4 + cq) * 512 + n) * 8 + i0;   // lo plane
    *(ushort4*)&Bpack[off0] = *(ushort4*)h;
    *(ushort4*)&Bpack[off1] = *(ushort4*)l;
    #pragma unroll
    for (int off = 32; off; off >>= 1) s += __shfl_down(s, off);
    if (t == 0) e2[n] = s;
}

// ---------------- kernel 2: DMA-pipelined split-bf16 MFMA GEMM ----------------
// grid 1024; block 512 (8 waves). R6 diagnosis: the compiler (VGPR_Count=72)
// never kept the source-level B double-buffer live -> per-step serialized
// load->waitcnt->mfma chains (~25K cy/step). Fix: B streams via
// global_load_lds DMA (no VGPRs, MLP by queue depth) into LDS dbuf;
// RAW s_barrier + hand-counted vmcnt(4) (never 0 mid-loop; __syncthreads
// would drain vmcnt(0) = the m97 stall). 16 phases (ct x hi/lo, 32KB each),
// prefetch distance 2. A in LDS (R3 proven layout). #pragma unroll 1 loop.
__launch_bounds__(512, 1)
__global__ void main_kernel(const float* __restrict__ pq,
                            const __bf16* __restrict__ Bpack,
                            const float* __restrict__ e2, P2* __restrict__ partials,
                            float* __restrict__ x2) {
    const int Mtile = blockIdx.x;
    const int tid  = threadIdx.x;
    const int wave = tid >> 6, lane = tid & 63;
    const int lm = lane & 15, quad = lane >> 4;
    const int b  = Mtile >> 6;
    const int s0 = (Mtile * 64) & 4095;

    __shared__ __attribute__((aligned(16))) __bf16 Afull[2][64][260]; // 66.5 KB
    __shared__ __attribute__((aligned(16))) __bf16 Bs[2][16384];      // 64 KB dbuf
    __shared__ float  xs[8][64];                                      // 2 KB
    __shared__ P2     mb[8][64];                                      // 8 KB

    floatx4 acc[4][4];
    #pragma unroll
    for (int i = 0; i < 4; ++i)
        #pragma unroll
        for (int j = 0; j < 4; ++j) acc[i][j] = (floatx4)0.f;

    // ---- prologue: pq loads first (oldest in vmcnt queue, drain naturally) --
    const float* pqA = pq + (size_t)b * (C_ * N_) + s0 + lane;
    float af[8][4];
    #pragma unroll
    for (int ct = 0; ct < 8; ++ct)
        #pragma unroll
        for (int i = 0; i < 4; ++i)
            af[ct][i] = pqA[(size_t)(ct * 32 + wave * 4 + i) * N_];

    // DMA one 32 KB slice (CT, PLANE): 8 waves x 4 chunks x 1 KB, linear copy.
    #define DMASLICE(CT, PLANE, BUF) { \
        const __bf16* sb_ = Bpack + (size_t)(CT) * 32768 + (PLANE) * 16384; \
        _Pragma("unroll") \
        for (int j_ = 0; j_ < 4; ++j_) { \
            int c_ = wave * 4 + j_; \
            __builtin_amdgcn_global_load_lds( \
                (const glob_bf16*)(sb_ + (size_t)(c_ * 64 + lane) * 8), \
                (lds_bf16*)&Bs[BUF][c_ * 512], 16, 0, 0); } }

    DMASLICE(0, 0, 0)     // hi(0) -> Bs[0]
    DMASLICE(0, 1, 1)     // lo(0) -> Bs[1]

    // ---- convert + stage A (hi/lo) to LDS ----
    float x2loc = 0.f;
    #pragma unroll
    for (int ct = 0; ct < 8; ++ct) {
        __bf16 h[4], l[4];
        #pragma unroll
        for (int i = 0; i < 4; ++i) {
            float a = af[ct][i];
            h[i] = (__bf16)a;
            l[i] = (__bf16)(a - (float)h[i]);
            x2loc = fmaf(a, a, x2loc);
        }
        *(ushort4*)&Afull[0][lane][ct * 32 + wave * 4] = *(ushort4*)h;
        *(ushort4*)&Afull[1][lane][ct * 32 + wave * 4] = *(ushort4*)l;
    }
    xs[wave][lane] = x2loc;

    const int kbase = wave * 64;
    float e2v[4];
    #pragma unroll
    for (int nt = 0; nt < 4; ++nt) e2v[nt] = e2[kbase + nt * 16 + lm];

    asm volatile("s_waitcnt lgkmcnt(0)" ::: "memory");  // A ds_writes drained
    asm volatile("s_waitcnt vmcnt(4)" ::: "memory");    // hi(0) arrived (lo(0) may fly)
    __builtin_amdgcn_s_barrier();
    asm volatile("" ::: "memory");

    // ---- 16-phase pipelined K-loop (compact code; uniform branches) ----
    #pragma unroll 1
    for (int ct = 0; ct < 8; ++ct) {
        const int col = ct * 32 + quad * 8;
        bf16x8 a1[4], a2[4], bb[4];
        #pragma unroll
        for (int mt = 0; mt < 4; ++mt) {
            a1[mt] = *(const bf16x8*)&Afull[0][mt * 16 + lm][col];
            a2[mt] = *(const bf16x8*)&Afull[1][mt * 16 + lm][col];
        }
        // ---- phase hi: Bs[0] = hi(ct): a1*bh + a2*bh (32 MFMA) ----
        #pragma unroll
        for (int nt = 0; nt < 4; ++nt)
            bb[nt] = *(const bf16x8*)&Bs[0][(quad * 512 + wave * 64 + nt * 16 + lm) * 8];
        #pragma unroll
        for (int nt = 0; nt < 4; ++nt)
            #pragma unroll
            for (int mt = 0; mt < 4; ++mt)
                acc[mt][nt] = __builtin_amdgcn_mfma_f32_16x16x32_bf16(a1[mt], bb[nt], acc[mt][nt], 0, 0, 0);
        #pragma unroll
        for (int nt = 0; nt < 4; ++nt)
            #pragma unroll
            for (int mt = 0; mt < 4; ++mt)
                acc[mt][nt] = __builtin_amdgcn_mfma_f32_16x16x32_bf16(a2[mt], bb[nt], acc[mt][nt], 0, 0, 0);
        asm volatile("" ::: "memory");
        __builtin_amdgcn_s_barrier();               // all readers of Bs[0] done
        asm volatile("" ::: "memory");
        if (ct < 7) { DMASLICE(ct + 1, 0, 0) }      // hi(ct+1) -> Bs[0]
        if (ct < 7) asm volatile("s_waitcnt vmcnt(4)" ::: "memory");  // lo(ct) ready
        else        asm volatile("s_waitcnt vmcnt(0)" ::: "memory");
        __builtin_amdgcn_s_barrier();
        asm volatile("" ::: "memory");
        // ---- phase lo: Bs[1] = lo(ct): a1*bl (16 MFMA) ----
        #pragma unroll
        for (int nt = 0; nt < 4; ++nt)
            bb[nt] = *(const bf16x8*)&Bs[1][(quad * 512 + wave * 64 + nt * 16 + lm) * 8];
        #pragma unroll
        for (int nt = 0; nt < 4; ++nt)
            #pragma unroll
            for (int mt = 0; mt < 4; ++mt)
                acc[mt][nt] = __builtin_amdgcn_mfma_f32_16x16x32_bf16(a1[mt], bb[nt], acc[mt][nt], 0, 0, 0);
        if (ct < 7) {
            asm volatile("" ::: "memory");
            __builtin_amdgcn_s_barrier();           // all readers of Bs[1] done
            asm volatile("" ::: "memory");
            DMASLICE(ct + 1, 1, 1)                  // lo(ct+1) -> Bs[1]
            asm volatile("s_waitcnt vmcnt(4)" ::: "memory");  // hi(ct+1) ready
            __builtin_amdgcn_s_barrier();
            asm volatile("" ::: "memory");
        }
    }

    // ---- epilogue: per-wave top-2 over its 64 codes -> 8-way LDS merge ----
    #pragma unroll
    for (int mt = 0; mt < 4; ++mt) {
        #pragma unroll
        for (int r = 0; r < 4; ++r) {
            float v1 = __builtin_inff(), v2 = __builtin_inff();
            int k1 = 0x7fffffff, k2 = 0x7fffffff;
            #pragma unroll
            for (int nt = 0; nt < 4; ++nt) {
                float v = fmaf(-2.f, acc[mt][nt][r], e2v[nt]);
                ins2(v, kbase + nt * 16 + lm, v1, k1, v2, k2);
            }
            #pragma unroll
            for (int m = 1; m < 16; m <<= 1) {
                float ov1 = __shfl_xor(v1, m); int ok1 = __shfl_xor(k1, m);
                float ov2 = __shfl_xor(v2, m); int ok2 = __shfl_xor(k2, m);
                ins2(ov1, ok1, v1, k1, v2, k2);
                ins2(ov2, ok2, v1, k1, v2, k2);
            }
            if (lm == 0) {
                P2 p; p.v1 = v1; p.k1 = k1; p.v2 = v2; p.k2 = k2;
                mb[wave][mt * 16 + quad * 4 + r] = p;
            }
        }
    }
    __syncthreads();

    if (tid < 64) {
        float v1 = __builtin_inff(), v2 = __builtin_inff();
        int k1 = 0x7fffffff, k2 = 0x7fffffff;
        float xsum = 0.f;
        #pragma unroll
        for (int w = 0; w < 8; ++w) {
            P2 p = mb[w][tid];
            ins2(p.v1, p.k1, v1, k1, v2, k2);
            ins2(p.v2, p.k2, v1, k1, v2, k2);
            xsum += xs[w][tid];
        }
        P2 p; p.v1 = v1; p.k1 = k1; p.v2 = v2; p.k2 = k2;
        partials[Mtile * 64 + tid] = p;
        x2[Mtile * 64 + tid] = xsum;
    }
}

// =================== UNCONDITIONAL PHASE DIAGNOSTICS =========================
// Old-structure phase bounds (R3/R5 environment). Visible in top-5 <=> that
// phase is pathological.

// ---- diag C: prologue + LDS A-reads + MFMAs with constant B, REP=4 ----------
__launch_bounds__(512, 4)
__global__ void diag_nold(const float* __restrict__ pq, float* __restrict__ sink) {
    __shared__ __attribute__((aligned(16))) __bf16 Afull[2][64][260];
    __shared__ float xs[8][64];
    __shared__ P2 mb[8][64];
    const int Mtile = blockIdx.x;
    const int tid = threadIdx.x, wave = tid >> 6, lane = tid & 63;
    const int lm = lane & 15, quad = lane >> 4;
    const int b = Mtile >> 6;
    const int s0 = (Mtile * 64) & 4095;
    mb[0][lane].k1 = 0;

    floatx4 acc[4][4];
    #pragma unroll
    for (int i = 0; i < 4; ++i)
        #pragma unroll
        for (int j = 0; j < 4; ++j) acc[i][j] = (floatx4)0.f;

    const float* pqA = pq + (size_t)b * (C_ * N_) + s0 + lane;
    float x2loc = 0.f;
    #pragma unroll
    for (int ct = 0; ct < 8; ++ct) {
        __bf16 h[4], l[4];
        #pragma unroll
        for (int i = 0; i < 4; ++i) {
            float a = pqA[(size_t)(ct * 32 + wave * 4 + i) * N_];
            h[i] = (__bf16)a;
            l[i] = (__bf16)(a - (float)h[i]);
            x2loc = fmaf(a, a, x2loc);
        }
        *(ushort4*)&Afull[0][lane][ct * 32 + wave * 4] = *(ushort4*)h;
        *(ushort4*)&Afull[1][lane][ct * 32 + wave * 4] = *(ushort4*)l;
    }
    xs[wave][lane] = x2loc;
    __syncthreads();

    bf16x8 bco;
    #pragma unroll
    for (int i = 0; i < 8; ++i) bco[i] = (__bf16)0.25f;

    #pragma unroll 1
    for (int rep = 0; rep < 4; ++rep) {
        #pragma unroll
        for (int ct = 0; ct < 8; ++ct) {
            bf16x8 a1[4];
            #pragma unroll
            for (int mt = 0; mt < 4; ++mt)
                a1[mt] = *(const bf16x8*)&Afull[0][mt * 16 + lm][ct * 32 + quad * 8];
            #pragma unroll
            for (int nt = 0; nt < 4; ++nt)
                #pragma unroll
                for (int mt = 0; mt < 4; ++mt)
                    acc[mt][nt] = __builtin_amdgcn_mfma_f32_16x16x32_bf16(a1[mt], bco, acc[mt][nt], 0, 0, 0);
            #pragma unroll
            for (int nt = 0; nt < 4; ++nt)
                #pragma unroll
                for (int mt = 0; mt < 4; ++mt)
                    acc[mt][nt] = __builtin_amdgcn_mfma_f32_16x16x32_bf16(a1[mt], bco, acc[mt][nt], 0, 0, 0);
            #pragma unroll
            for (int mt = 0; mt < 4; ++mt) {
                bf16x8 a2 = *(const bf16x8*)&Afull[1][mt * 16 + lm][ct * 32 + quad * 8];
                #pragma unroll
                for (int nt = 0; nt < 4; ++nt)
                    acc[mt][nt] = __builtin_amdgcn_mfma_f32_16x16x32_bf16(a2, bco, acc[mt][nt], 0, 0, 0);
            }
        }
    }
    float t = 0.f;
    #pragma unroll
    for (int mt = 0; mt < 4; ++mt)
        #pragma unroll
        for (int nt = 0; nt < 4; ++nt)
            #pragma unroll
            for (int r = 0; r < 4; ++r) t += acc[mt][nt][r];
    if (t == 1234.5678f && mb[0][lane].k1 == 77) sink[0] = t;
}

// ---- diag E: prologue + epilogue only (fake acc), REP=3 ---------------------
__launch_bounds__(512, 4)
__global__ void diag_epi(const float* __restrict__ pq, const float* __restrict__ e2,
                         float* __restrict__ sink) {
    __shared__ __attribute__((aligned(16))) __bf16 Afull[2][64][260];
    __shared__ float xs[8][64];
    __shared__ P2 mb[8][64];
    const int Mtile = blockIdx.x;
    const int tid = threadIdx.x, wave = tid >> 6, lane = tid & 63;
    const int lm = lane & 15, quad = lane >> 4;
    const int b = Mtile >> 6;
    const int s0 = (Mtile * 64) & 4095;

    const float* pqA = pq + (size_t)b * (C_ * N_) + s0 + lane;
    float x2loc = 0.f;
    #pragma unroll
    for (int ct = 0; ct < 8; ++ct) {
        __bf16 h[4], l[4];
        #pragma unroll
        for (int i = 0; i < 4; ++i) {
            float a = pqA[(size_t)(ct * 32 + wave * 4 + i) * N_];
            h[i] = (__bf16)a;
            l[i] = (__bf16)(a - (float)h[i]);
            x2loc = fmaf(a, a, x2loc);
        }
        *(ushort4*)&Afull[0][lane][ct * 32 + wave * 4] = *(ushort4*)h;
        *(ushort4*)&Afull[1][lane][ct * 32 + wave * 4] = *(ushort4*)l;
    }
    xs[wave][lane] = x2loc;
    __syncthreads();

    floatx4 acc[4][4];
    #pragma unroll
    for (int i = 0; i < 4; ++i)
        #pragma unroll
        for (int j = 0; j < 4; ++j)
            #pragma unroll
            for (int r = 0; r < 4; ++r) acc[i][j][r] = x2loc * (0.01f * (i * 16 + j * 4 + r));

    const int kbase = wave * 64;
    float e2v[4];
    #pragma unroll
    for (int nt = 0; nt < 4; ++nt) e2v[nt] = e2[kbase + nt * 16 + lm];

    float keep = 0.f;
    #pragma unroll 1
    for (int rep = 0; rep < 3; ++rep) {
        #pragma unroll
        for (int mt = 0; mt < 4; ++mt) {
            #pragma unroll
            for (int r = 0; r < 4; ++r) {
                float v1 = __builtin_inff(), v2 = __builtin_inff();
                int k1 = 0x7fffffff, k2 = 0x7fffffff;
                #pragma unroll
                for (int nt = 0; nt < 4; ++nt) {
                    float v = fmaf(-2.f, acc[mt][nt][r], e2v[nt]);
                    ins2(v, kbase + nt * 16 + lm, v1, k1, v2, k2);
                }
                #pragma unroll
                for (int m = 1; m < 16; m <<= 1) {
                    float ov1 = __shfl_xor(v1, m); int ok1 = __shfl_xor(k1, m);
                    float ov2 = __shfl_xor(v2, m); int ok2 = __shfl_xor(k2, m);
                    ins2(ov1, ok1, v1, k1, v2, k2);
                    ins2(ov2, ok2, v1, k1, v2, k2);
                }
                if (lm == 0) {
                    P2 p; p.v1 = v1; p.k1 = k1; p.v2 = v2; p.k2 = k2;
                    mb[wave][mt * 16 + quad * 4 + r] = p;
                }
            }
        }
        __syncthreads();
        if (tid < 64) {
            float v1 = __builtin_inff(), v2 = __builtin_inff();
            int k1 = 0x7fffffff, k2 = 0x7fffffff;
            float xsum = 0.f;
            #pragma unroll
            for (int w = 0; w < 8; ++w) {
                P2 p = mb[w][tid];
                ins2(p.v1, p.k1, v1, k1, v2, k2);
                ins2(p.v2, p.k2, v1, k1, v2, k2);
                xsum += xs[w][tid];
            }
            keep += v1 + v2 + (float)(k1 ^ k2) + xsum;
        }
        __syncthreads();
    }
    if (keep == 1234.5678f) sink[0] = keep;
}

// ---------------- kernel 3: fused refine + loss + gather ----------------------
#define MARGIN 0.05f
__global__ void scatter_merge_kernel(const P2* __restrict__ partials,
                                     const float* __restrict__ x2arr,
                                     const float* __restrict__ pq,
                                     const float* __restrict__ cb,
                                     double* __restrict__ lossAcc,
                                     float* __restrict__ out) {
    int ntile = blockIdx.x, b = blockIdx.y, tid = threadIdx.x;
    int wave = tid >> 6;
    __shared__ int idxs[64];
    __shared__ double lred[4];
    __shared__ float tile[64][65];

    double myloss = 0.0;
    if (tid < 64) {
        int p = ntile * 64 + tid;
        int s = ((p & 63) << 6) | (p >> 6);
        int row = (b << 12) | s;
        P2 pp = partials[row];
        float v1 = pp.v1, v2 = pp.v2;
        int k1 = pp.k1, k2 = pp.k2;
        int kwin = k1;
        double d2min;
        if (v2 - v1 < MARGIN) {
            const float* xp  = pq + (size_t)b * (C_ * N_) + s;
            const float* ca  = cb + (size_t)k1 * C_;
            const float* cbp = cb + (size_t)k2 * C_;
            double da = 0.0, db = 0.0;
            for (int c = 0; c < C_; ++c) {
                double xv = (double)xp[(size_t)c * N_];
                double ea = xv - (double)ca[c];  da += ea * ea;
                double eb = xv - (double)cbp[c]; db += eb * eb;
            }
            if (db < da || (db == da && k2 < k1)) { kwin = k2; d2min = db; }
            else d2min = da;
        } else {
            d2min = (double)(x2arr[row] + v1);
        }
        idxs[tid] = kwin;
        myloss = d2min;
    }
    double sd = myloss;
    #pragma unroll
    for (int off = 32; off; off >>= 1) sd += __shfl_down(sd, off);
    if ((tid & 63) == 0) lred[wave] = sd;
    __syncthreads();
    if (tid == 0) atomicAdd(lossAcc, lred[0] + lred[1] + lred[2] + lred[3]);

    for (int cc = 0; cc < 4; ++cc) {
        int c0 = cc * 64;
        #pragma unroll
        for (int pp = 0; pp < 16; ++pp) {
            int i = pp * 4 + (tid >> 6);
            int c = tid & 63;
            tile[i][c] = cb[(size_t)idxs[i] * C_ + c0 + c];
        }
        __syncthreads();
        #pragma unroll
        for (int pp = 0; pp < 16; ++pp) {
            int cl = pp * 4 + (tid >> 6);
            int nl = tid & 63;
            out[((size_t)(b * C_ + c0 + cl)) * N_ + ntile * 64 + nl] = tile[nl][cl];
        }
        __syncthreads();
    }
}

// ---------------- kernel 4: loss finalize ------------------------------------
__global__ void finalize_kernel(const double* __restrict__ lossAcc, float* __restrict__ out) {
    out[(size_t)B_ * C_ * N_] =
        (float)(1.25 * (*lossAcc) / (double)((size_t)B_ * N_ * C_));
}

// ---------------- launch ------------------------------------------------------
extern "C" void kernel_launch(void* const* d_in, const int* in_sizes, int n_in,
                              void* d_out, int out_size, void* d_ws, size_t ws_size,
                              hipStream_t stream) {
    const float* pq = (const float*)d_in[0];   // [16,256,64,64]
    const float* cb = (const float*)d_in[1];   // [512,256]
    float* out = (float*)d_out;                // 4194304 out + 1 loss
    char* ws = (char*)d_ws;
    double* lossAcc = (double*)ws;                            // 8 B
    float*  sink  = (float*)(ws + 8);                         // diag sink (dead)
    float*  e2    = (float*)(ws + 16);                        // 2 KB
    float*  x2    = (float*)(ws + 16 + 2048);                 // 256 KB
    __bf16* Bpack = (__bf16*)(ws + 16 + 2048 + 262144);       // 512 KB
    P2* partials  = (P2*)(ws + 16 + 2048 + 262144 + 524288);  // 1 MB

    prep_kernel<<<K_, 64, 0, stream>>>(cb, e2, Bpack, lossAcc);
    main_kernel<<<1024, 512, 0, stream>>>(pq, Bpack, e2, partials, x2);
    scatter_merge_kernel<<<dim3(HW_, B_), 256, 0, stream>>>(partials, x2, pq, cb, lossAcc, out);
    finalize_kernel<<<1, 1, 0, stream>>>(lossAcc, out);

    // phase diagnostics (unconditional; outputs untouched)
    diag_nold<<<1024, 512, 0, stream>>>(pq, sink);
    diag_epi<<<1024, 512, 0, stream>>>(pq, e2, sink);
}

// Round 8
// 331.885 us; speedup vs baseline: 5.2307x; 5.2307x over previous
//
#include <hip/hip_runtime.h>
#include <cstdint>
#include <cstddef>

#define B_    16
#define C_    256
#define HW_   64
#define N_    4096      // 64*64 spatial
#define K_    512
#define NROW_ 65536     // B_*N_

typedef __attribute__((ext_vector_type(8))) __bf16 bf16x8;
typedef __attribute__((ext_vector_type(4))) float floatx4;

struct P2 { float v1; int k1; float v2; int k2; };

__device__ __forceinline__ bool lexless(float v, int k, float bv, int bk) {
    return (v < bv) || (v == bv && k < bk);
}
__device__ __forceinline__ void ins2(float v, int k, float& v1, int& k1, float& v2, int& k2) {
    if (lexless(v, k, v1, k1)) { v2 = v1; k2 = k1; v1 = v; k1 = k; }
    else if (lexless(v, k, v2, k2)) { v2 = v; k2 = k; }
}
// 16-B LDS record moves (force b128)
__device__ __forceinline__ P2 ldP(const P2* p) {
    uint4 u = *(const uint4*)p;
    P2 r; r.v1 = __uint_as_float(u.x); r.k1 = (int)u.y;
    r.v2 = __uint_as_float(u.z); r.k2 = (int)u.w; return r;
}
__device__ __forceinline__ void stP(P2* p, float v1, int k1, float v2, int k2) {
    uint4 u; u.x = __float_as_uint(v1); u.y = (unsigned)k1;
    u.z = __float_as_uint(v2); u.w = (unsigned)k2;
    *(uint4*)p = u;
}
__device__ __forceinline__ void insP(P2 p, float& v1, int& k1, float& v2, int& k2) {
    ins2(p.v1, p.k1, v1, k1, v2, k2);
    ins2(p.v2, p.k2, v1, k1, v2, k2);
}

// Bpack layout: [ct 8][plane 2][cq 4][n 512][i 8] bf16, 512 KB.

// ---------------- kernel 1: codebook prep: e2 + packed bf16 hi/lo tiles -------
__global__ void prep_kernel(const float* __restrict__ cb, float* __restrict__ e2,
                            __bf16* __restrict__ Bpack, double* __restrict__ lossAcc) {
    int n = blockIdx.x, t = threadIdx.x;
    if (n == 0 && t == 0) *lossAcc = 0.0;
    float4 v = *(const float4*)(cb + (size_t)n * C_ + t * 4);
    float vv[4] = {v.x, v.y, v.z, v.w};
    __bf16 h[4], l[4];
    float s = 0.f;
    #pragma unroll
    for (int i = 0; i < 4; ++i) {
        h[i] = (__bf16)vv[i];
        l[i] = (__bf16)(vv[i] - (float)h[i]);
        s = fmaf(vv[i], vv[i], s);
    }
    int ct = t >> 3, cq = (t >> 1) & 3, i0 = (t & 1) * 4;
    size_t base = (size_t)ct * 32768;
    size_t off0 = base + ((size_t)(0 * 4 + cq) * 512 + n) * 8 + i0;   // hi plane
    size_t off1 = base + ((size_t)(1 * 4 + cq) * 512 + n) * 8 + i0;   // lo plane
    *(ushort4*)&Bpack[off0] = *(ushort4*)h;
    *(ushort4*)&Bpack[off1] = *(ushort4*)l;
    #pragma unroll
    for (int off = 32; off; off >>= 1) s += __shfl_down(s, off);
    if (t == 0) e2[n] = s;
}

// ---------------- kernel 2: split-bf16 MFMA GEMM + SHUFFLE-FREE top-2 ---------
// R7 finding: the old epilogue's 256 ds_bpermute/wave (__shfl_xor butterfly)
// cost ~220 us at 8 waves/block -- it dominated every round; GEMM is ~100 us.
// New epilogue: LDS-staged tree (ds_read/write_b128 + serial ins2 scans),
// ZERO cross-lane ops. K-loop: R3's barrier-free version, unchanged.
__launch_bounds__(512, 4)
__global__ void main_kernel(const float* __restrict__ pq,
                            const __bf16* __restrict__ Bpack,
                            const float* __restrict__ e2, P2* __restrict__ partials,
                            float* __restrict__ x2) {
    const int Mtile = blockIdx.x;
    const int tid  = threadIdx.x;
    const int wave = tid >> 6, lane = tid & 63;
    const int lm = lane & 15, quad = lane >> 4;
    const int b  = Mtile >> 6;
    const int s0 = (Mtile * 64) & 4095;

    __shared__ __attribute__((aligned(16))) __bf16 Afull[2][64][260]; // 66.5 KB
    __shared__ float  xs[8][64];                                      // 2 KB

    floatx4 acc[4][4];
    #pragma unroll
    for (int i = 0; i < 4; ++i)
        #pragma unroll
        for (int j = 0; j < 4; ++j) acc[i][j] = (floatx4)0.f;

    // ---- prologue: 32 independent coalesced pq loads ----
    const float* pqA = pq + (size_t)b * (C_ * N_) + s0 + lane;
    float af[8][4];
    #pragma unroll
    for (int ct = 0; ct < 8; ++ct)
        #pragma unroll
        for (int i = 0; i < 4; ++i)
            af[ct][i] = pqA[(size_t)(ct * 32 + wave * 4 + i) * N_];

    float x2loc = 0.f;
    #pragma unroll
    for (int ct = 0; ct < 8; ++ct) {
        __bf16 h[4], l[4];
        #pragma unroll
        for (int i = 0; i < 4; ++i) {
            float a = af[ct][i];
            h[i] = (__bf16)a;
            l[i] = (__bf16)(a - (float)h[i]);
            x2loc = fmaf(a, a, x2loc);
        }
        *(ushort4*)&Afull[0][lane][ct * 32 + wave * 4] = *(ushort4*)h;
        *(ushort4*)&Afull[1][lane][ct * 32 + wave * 4] = *(ushort4*)l;
    }
    xs[wave][lane] = x2loc;
    __syncthreads();

    // ---- barrier-free K-loop (R3; GEMM ~100 us) ----
    #pragma unroll
    for (int ct = 0; ct < 8; ++ct) {
        const __bf16* bp = Bpack + (size_t)ct * 32768
                         + ((size_t)quad * 512 + wave * 64 + lm) * 8;
        bf16x8 bh[4], bl[4];
        #pragma unroll
        for (int nt = 0; nt < 4; ++nt)
            bh[nt] = *(const bf16x8*)(bp + (size_t)nt * 128);
        #pragma unroll
        for (int nt = 0; nt < 4; ++nt)
            bl[nt] = *(const bf16x8*)(bp + 16384 + (size_t)nt * 128);

        bf16x8 a1[4];
        #pragma unroll
        for (int mt = 0; mt < 4; ++mt)
            a1[mt] = *(const bf16x8*)&Afull[0][mt * 16 + lm][ct * 32 + quad * 8];

        #pragma unroll
        for (int nt = 0; nt < 4; ++nt)
            #pragma unroll
            for (int mt = 0; mt < 4; ++mt)
                acc[mt][nt] = __builtin_amdgcn_mfma_f32_16x16x32_bf16(a1[mt], bh[nt], acc[mt][nt], 0, 0, 0);
        #pragma unroll
        for (int nt = 0; nt < 4; ++nt)
            #pragma unroll
            for (int mt = 0; mt < 4; ++mt)
                acc[mt][nt] = __builtin_amdgcn_mfma_f32_16x16x32_bf16(a1[mt], bl[nt], acc[mt][nt], 0, 0, 0);
        #pragma unroll
        for (int mt = 0; mt < 4; ++mt) {
            bf16x8 a2 = *(const bf16x8*)&Afull[1][mt * 16 + lm][ct * 32 + quad * 8];
            #pragma unroll
            for (int nt = 0; nt < 4; ++nt)
                acc[mt][nt] = __builtin_amdgcn_mfma_f32_16x16x32_bf16(a2, bh[nt], acc[mt][nt], 0, 0, 0);
        }
    }

    // ---- epilogue v2: shuffle-free LDS tree over dead Afull ----
    const int kbase = wave * 64;
    float e2v[4];
    #pragma unroll
    for (int nt = 0; nt < 4; ++nt) e2v[nt] = e2[kbase + nt * 16 + lm];

    P2* Lbuf = (P2*)&Afull[0][0][0];   // [16][129] = 33,024 B (<= 33,280)
    P2* L2b  = (P2*)&Afull[1][0][0];   // [16][33]  =  8,448 B

    #pragma unroll
    for (int mt = 0; mt < 4; ++mt) {
        __syncthreads();   // K-loop / previous chunk reads of this region done
        // stage A: per thread, top-2 over its 4 nt-candidates, per row r
        #pragma unroll
        for (int r = 0; r < 4; ++r) {
            float v1 = __builtin_inff(), v2 = __builtin_inff();
            int k1 = 0x7fffffff, k2 = 0x7fffffff;
            #pragma unroll
            for (int nt = 0; nt < 4; ++nt) {
                float v = fmaf(-2.f, acc[mt][nt][r], e2v[nt]);
                ins2(v, kbase + nt * 16 + lm, v1, k1, v2, k2);
            }
            stP(&Lbuf[(quad * 4 + r) * 129 + wave * 16 + lm], v1, k1, v2, k2);
        }
        __syncthreads();
        // stage B: 512 threads, each merges 4 records of one row
        {
            int row = tid >> 5, part = tid & 31;
            float v1 = __builtin_inff(), v2 = __builtin_inff();
            int k1 = 0x7fffffff, k2 = 0x7fffffff;
            #pragma unroll
            for (int j = 0; j < 4; ++j)
                insP(ldP(&Lbuf[row * 129 + part + 32 * j]), v1, k1, v2, k2);
            stP(&L2b[row * 33 + part], v1, k1, v2, k2);
        }
        __syncthreads();
        // stage C1: 128 threads, 32 -> 8 per row (out into freed Lbuf slots)
        if (tid < 128) {
            int row = tid >> 3, q = tid & 7;
            float v1 = __builtin_inff(), v2 = __builtin_inff();
            int k1 = 0x7fffffff, k2 = 0x7fffffff;
            #pragma unroll
            for (int j = 0; j < 4; ++j)
                insP(ldP(&L2b[row * 33 + q + 8 * j]), v1, k1, v2, k2);
            stP(&Lbuf[row * 129 + q], v1, k1, v2, k2);
        }
        __syncthreads();
        // stage C2: 16 threads, 8 -> final top-2 per row, straight to global
        if (tid < 16) {
            int row = tid;
            float v1 = __builtin_inff(), v2 = __builtin_inff();
            int k1 = 0x7fffffff, k2 = 0x7fffffff;
            #pragma unroll
            for (int j = 0; j < 8; ++j)
                insP(ldP(&Lbuf[row * 129 + j]), v1, k1, v2, k2);
            P2 p; p.v1 = v1; p.k1 = k1; p.v2 = v2; p.k2 = k2;
            partials[Mtile * 64 + mt * 16 + row] = p;
        }
    }

    // x2 (xs written before the prologue barrier -> visible)
    if (tid < 64) {
        float xsum = 0.f;
        #pragma unroll
        for (int w = 0; w < 8; ++w) xsum += xs[w][tid];
        x2[Mtile * 64 + tid] = xsum;
    }
}

// ---------------- kernel 3: fused refine + loss + gather ----------------------
#define MARGIN 0.05f
__global__ void scatter_merge_kernel(const P2* __restrict__ partials,
                                     const float* __restrict__ x2arr,
                                     const float* __restrict__ pq,
                                     const float* __restrict__ cb,
                                     double* __restrict__ lossAcc,
                                     float* __restrict__ out) {
    int ntile = blockIdx.x, b = blockIdx.y, tid = threadIdx.x;
    int wave = tid >> 6;
    __shared__ int idxs[64];
    __shared__ double lred[4];
    __shared__ float tile[64][65];

    double myloss = 0.0;
    if (tid < 64) {
        int p = ntile * 64 + tid;
        int s = ((p & 63) << 6) | (p >> 6);
        int row = (b << 12) | s;
        P2 pp = partials[row];
        float v1 = pp.v1, v2 = pp.v2;
        int k1 = pp.k1, k2 = pp.k2;
        int kwin = k1;
        double d2min;
        if (v2 - v1 < MARGIN) {
            const float* xp  = pq + (size_t)b * (C_ * N_) + s;
            const float* ca  = cb + (size_t)k1 * C_;
            const float* cbp = cb + (size_t)k2 * C_;
            double da = 0.0, db = 0.0;
            for (int c = 0; c < C_; ++c) {
                double xv = (double)xp[(size_t)c * N_];
                double ea = xv - (double)ca[c];  da += ea * ea;
                double eb = xv - (double)cbp[c]; db += eb * eb;
            }
            if (db < da || (db == da && k2 < k1)) { kwin = k2; d2min = db; }
            else d2min = da;
        } else {
            d2min = (double)(x2arr[row] + v1);
        }
        idxs[tid] = kwin;
        myloss = d2min;
    }
    double sd = myloss;
    #pragma unroll
    for (int off = 32; off; off >>= 1) sd += __shfl_down(sd, off);
    if ((tid & 63) == 0) lred[wave] = sd;
    __syncthreads();
    if (tid == 0) atomicAdd(lossAcc, lred[0] + lred[1] + lred[2] + lred[3]);

    for (int cc = 0; cc < 4; ++cc) {
        int c0 = cc * 64;
        #pragma unroll
        for (int pp = 0; pp < 16; ++pp) {
            int i = pp * 4 + (tid >> 6);
            int c = tid & 63;
            tile[i][c] = cb[(size_t)idxs[i] * C_ + c0 + c];
        }
        __syncthreads();
        #pragma unroll
        for (int pp = 0; pp < 16; ++pp) {
            int cl = pp * 4 + (tid >> 6);
            int nl = tid & 63;
            out[((size_t)(b * C_ + c0 + cl)) * N_ + ntile * 64 + nl] = tile[nl][cl];
        }
        __syncthreads();
    }
}

// ---------------- kernel 4: loss finalize ------------------------------------
__global__ void finalize_kernel(const double* __restrict__ lossAcc, float* __restrict__ out) {
    out[(size_t)B_ * C_ * N_] =
        (float)(1.25 * (*lossAcc) / (double)((size_t)B_ * N_ * C_));
}

// ---------------- launch ------------------------------------------------------
extern "C" void kernel_launch(void* const* d_in, const int* in_sizes, int n_in,
                              void* d_out, int out_size, void* d_ws, size_t ws_size,
                              hipStream_t stream) {
    const float* pq = (const float*)d_in[0];   // [16,256,64,64]
    const float* cb = (const float*)d_in[1];   // [512,256]
    float* out = (float*)d_out;                // 4194304 out + 1 loss
    char* ws = (char*)d_ws;
    double* lossAcc = (double*)ws;                            // 16 B
    float*  e2    = (float*)(ws + 16);                        // 2 KB
    float*  x2    = (float*)(ws + 16 + 2048);                 // 256 KB
    __bf16* Bpack = (__bf16*)(ws + 16 + 2048 + 262144);       // 512 KB
    P2* partials  = (P2*)(ws + 16 + 2048 + 262144 + 524288);  // 1 MB

    prep_kernel<<<K_, 64, 0, stream>>>(cb, e2, Bpack, lossAcc);
    main_kernel<<<1024, 512, 0, stream>>>(pq, Bpack, e2, partials, x2);
    scatter_merge_kernel<<<dim3(HW_, B_), 256, 0, stream>>>(partials, x2, pq, cb, lossAcc, out);
    finalize_kernel<<<1, 1, 0, stream>>>(lossAcc, out);
}